// Round 10
// baseline (122.085 us; speedup 1.0000x reference)
//
#include <hip/hip_runtime.h>

#define BN_B 32
#define BN_N 65536
#define THREADS 256
#define BLOCKS_PER_B 64

// ---- workspace layout ----
// [0, 2048*27*4)        partials (221184 B)
// [CNT_OFF + b*128)     per-batch arrival counters (int, 128B stride)
// [STATE_OFF, +33.6MB)  fp16 per-point state
#define CNT_OFF (256 * 1024)
#define STATE_OFF (512 * 1024)
#define STATE_BYTES ((size_t)BN_B * BN_N * 16)
#define WS_NEEDED (STATE_OFF + STATE_BYTES)

typedef _Float16 half_t;
union HPack { half_t h[2]; unsigned int u; };
struct alignas(16) Half8 { half_t h[8]; };
union StateU { Half8 s; uint4 u; };

__device__ __forceinline__ unsigned int packh(float a, float b) {
    HPack p; p.h[0] = (half_t)a; p.h[1] = (half_t)b; return p.u;
}

// Per-point math. Loads 18 floats.
__device__ __forceinline__ void point_core(
    const float* __restrict__ r, const float* __restrict__ w,
    const float* __restrict__ J_p, const float* __restrict__ J_d,
    size_t p, float lam,
    float jpa[6], float jpb[6], float& c, float& cr0, float& cr1,
    float hpd[6], float& gd, float& ihdd)
{
    float2 wv = *(const float2*)(w + p * 2);
    float2 rv = *(const float2*)(r + p * 2);
    float2 jd = *(const float2*)(J_d + p * 2);
    float4 jp0 = *(const float4*)(J_p + p * 12);
    float4 jp1 = *(const float4*)(J_p + p * 12 + 4);
    float4 jp2 = *(const float4*)(J_p + p * 12 + 8);
    c = wv.x;
    float nl = wv.y;
    jpa[0] = jp0.x; jpa[1] = jp0.y; jpa[2] = jp0.z; jpa[3] = jp0.w; jpa[4] = jp1.x; jpa[5] = jp1.y;
    jpb[0] = jp1.z; jpb[1] = jp1.w; jpb[2] = jp2.x; jpb[3] = jp2.y; jpb[4] = jp2.z; jpb[5] = jp2.w;
    float cjd0 = c * jd.x, cjd1 = c * jd.y;
#pragma unroll
    for (int i = 0; i < 6; ++i) hpd[i] = jpa[i] * cjd0 + jpb[i] * cjd1;
    float hdd = jd.x * cjd0 + jd.y * cjd1;
    cr0 = c * rv.x; cr1 = c * rv.y;
    gd = jd.x * cr0 + jd.y * cr1;
    ihdd = 1.0f / (hdd + lam + nl + 1e-6f);
}

// 6x6 solve (LDS matrix, 1 thread). As is [6][7] augmented.
__device__ __forceinline__ void solve6(volatile float As[6][7], float x[6]) {
    for (int col = 0; col < 6; ++col) {
        int piv = col;
        float best = fabsf(As[col][col]);
        for (int rw = col + 1; rw < 6; ++rw) {
            float v = fabsf(As[rw][col]);
            if (v > best) { best = v; piv = rw; }
        }
        if (piv != col) {
            for (int j = 0; j < 7; ++j) {
                float tmp = As[col][j]; As[col][j] = As[piv][j]; As[piv][j] = tmp;
            }
        }
        float inv = 1.0f / As[col][col];
        for (int rw = col + 1; rw < 6; ++rw) {
            float f = As[rw][col] * inv;
            for (int j = col; j < 7; ++j) As[rw][j] -= f * As[col][j];
        }
    }
    for (int i = 5; i >= 0; --i) {
        float s = As[i][6];
        for (int j = i + 1; j < 6; ++j) s -= As[i][j] * x[j];
        x[i] = s / As[i][i];
    }
}

// ============ kernel A: reduce + fp16 state + last-block solve ============
// Point loop is ROLLED (#pragma unroll 1): unrolling x4 doubles VGPR (104 in
// R9) and halves occupancy -> 2.3x slowdown. Rolled = 48-56 VGPR.
template <bool WRITE_STATE>
__global__ __launch_bounds__(THREADS) void k_reduce_solve(
    const float* __restrict__ r, const float* __restrict__ w,
    const float* __restrict__ J_p, const float* __restrict__ J_d,
    const float* __restrict__ lmbda, char* __restrict__ ws,
    float* __restrict__ out)
{
    float* partials = (float*)ws;
    int*   cnt      = (int*)(ws + CNT_OFF);              // stride 32 ints/batch
    uint4* state    = (uint4*)(ws + STATE_OFF);

    const int b   = blockIdx.y;
    const int blk = blockIdx.x;
    const float lam = lmbda[0];

    float acc[27];
#pragma unroll
    for (int i = 0; i < 27; ++i) acc[i] = 0.0f;

    const int n0 = blk * (BN_N / BLOCKS_PER_B);
    const int n1 = n0 + (BN_N / BLOCKS_PER_B);
    const size_t baseP = (size_t)b * BN_N;

#pragma unroll 1
    for (int n = n0 + (int)threadIdx.x; n < n1; n += THREADS) {
        size_t p = baseP + n;
        float jpa[6], jpb[6], hpd[6];
        float c, cr0, cr1, gd, ihdd;
        point_core(r, w, J_p, J_d, p, lam, jpa, jpb, c, cr0, cr1, hpd, gd, ihdd);

        uint4 su;
        float hs[6];
        int t = 0;
#pragma unroll
        for (int i = 0; i < 6; ++i) {
            float ca = c * jpa[i];
            float cb = c * jpb[i];
            hs[i] = ihdd * hpd[i];
#pragma unroll
            for (int j = i; j < 6; ++j, ++t)
                acc[t] += ca * jpa[j] + cb * jpb[j] - hs[i] * hpd[j];
            acc[21 + i] += jpa[i] * cr0 + jpb[i] * cr1 - hs[i] * gd;
        }
        if (WRITE_STATE) {
            su.x = packh(hs[0], hs[1]);
            su.y = packh(hs[2], hs[3]);
            su.z = packh(hs[4], hs[5]);
            su.w = packh(ihdd * gd, 0.0f);
            state[p] = su;
        }
    }

    // Wave reduce, then cross-wave via LDS.
#pragma unroll
    for (int i = 0; i < 27; ++i) {
        float v = acc[i];
#pragma unroll
        for (int off = 32; off > 0; off >>= 1) v += __shfl_down(v, off);
        acc[i] = v;
    }

    __shared__ float red[4][27];
    __shared__ float As[6][7];
    __shared__ int amLast;
    {
        const int wave = threadIdx.x >> 6;
        const int lane = threadIdx.x & 63;
        if (lane == 0) {
#pragma unroll
            for (int i = 0; i < 27; ++i) red[wave][i] = acc[i];
        }
    }
    __syncthreads();
    if (threadIdx.x < 27) {
        partials[((size_t)b * BLOCKS_PER_B + blk) * 27 + threadIdx.x] =
            red[0][threadIdx.x] + red[1][threadIdx.x] +
            red[2][threadIdx.x] + red[3][threadIdx.x];
    }
    // __syncthreads drains vmcnt, so the partials stores above are complete
    // before thread 0's release-add publishes them.
    __syncthreads();
    if (threadIdx.x == 0) {
        int old = __hip_atomic_fetch_add(&cnt[b * 32], 1, __ATOMIC_ACQ_REL,
                                         __HIP_MEMORY_SCOPE_AGENT);
        amLast = (old == BLOCKS_PER_B - 1);
    }
    __syncthreads();

    if (amLast) {
        __builtin_amdgcn_fence(__ATOMIC_ACQUIRE, "agent");
        if (threadIdx.x < 27) {
            float s = 0.0f;
            for (int c2 = 0; c2 < BLOCKS_PER_B; ++c2)
                s += partials[((size_t)b * BLOCKS_PER_B + c2) * 27 + threadIdx.x];
            red[0][threadIdx.x] = s;
        }
        __syncthreads();
        if (threadIdx.x == 0) {
            int t = 0;
            for (int i = 0; i < 6; ++i)
                for (int j = i; j < 6; ++j, ++t) { As[i][j] = red[0][t]; As[j][i] = red[0][t]; }
            for (int i = 0; i < 6; ++i) As[i][i] += lam + 0.001f;
            for (int i = 0; i < 6; ++i) As[i][6] = red[0][21 + i];
            float x[6];
            solve6(As, x);
            for (int i = 0; i < 6; ++i) out[b * 6 + i] = x[i];
        }
    }
}

// ============ kernel B: depth from fp16 state (16B/point) ============
__global__ __launch_bounds__(THREADS) void k_depth2(
    const uint4* __restrict__ state, const float* __restrict__ dp,
    float* __restrict__ out_depth)
{
    const int b = blockIdx.y;
    const int blk = blockIdx.x;
    float d[6];
#pragma unroll
    for (int i = 0; i < 6; ++i) d[i] = dp[b * 6 + i];

    const int n0 = blk * (BN_N / BLOCKS_PER_B);
    const int n1 = n0 + (BN_N / BLOCKS_PER_B);
    const size_t baseP = (size_t)b * BN_N;

#pragma unroll 1
    for (int n = n0 + (int)threadIdx.x; n < n1; n += THREADS) {
        size_t p = baseP + n;
        StateU su;
        su.u = state[p];
        float v = 0.0f;
#pragma unroll
        for (int i = 0; i < 6; ++i) v += (float)su.s.h[i] * d[i];
        out_depth[p] = (float)su.s.h[6] - v;
    }
}

// ============ fallback depth (recompute) if ws too small ============
__global__ __launch_bounds__(THREADS) void k_depth_rc(
    const float* __restrict__ r, const float* __restrict__ w,
    const float* __restrict__ J_p, const float* __restrict__ J_d,
    const float* __restrict__ lmbda, const float* __restrict__ dp,
    float* __restrict__ out_depth)
{
    const int b = blockIdx.y;
    const int blk = blockIdx.x;
    const float lam = lmbda[0];
    float d[6];
#pragma unroll
    for (int i = 0; i < 6; ++i) d[i] = dp[b * 6 + i];

    const int n0 = blk * (BN_N / BLOCKS_PER_B);
    const int n1 = n0 + (BN_N / BLOCKS_PER_B);
    const size_t baseP = (size_t)b * BN_N;

#pragma unroll 1
    for (int n = n0 + (int)threadIdx.x; n < n1; n += THREADS) {
        size_t p = baseP + n;
        float jpa[6], jpb[6], hpd[6];
        float c, cr0, cr1, gd, ihdd;
        point_core(r, w, J_p, J_d, p, lam, jpa, jpb, c, cr0, cr1, hpd, gd, ihdd);
        float v = hpd[0] * d[0] + hpd[1] * d[1] + hpd[2] * d[2] +
                  hpd[3] * d[3] + hpd[4] * d[4] + hpd[5] * d[5];
        out_depth[p] = ihdd * (gd - v);
    }
}

extern "C" void kernel_launch(void* const* d_in, const int* in_sizes, int n_in,
                              void* d_out, int out_size, void* d_ws, size_t ws_size,
                              hipStream_t stream) {
    const float* r     = (const float*)d_in[0];
    const float* w     = (const float*)d_in[1];
    const float* J_p   = (const float*)d_in[2];
    const float* J_d   = (const float*)d_in[3];
    const float* lmbda = (const float*)d_in[4];
    float* out = (float*)d_out;
    char* ws = (char*)d_ws;

    // Reset per-batch arrival counters (ws persists across graph replays).
    hipMemsetAsync(ws + CNT_OFF, 0, 4096, stream);

    dim3 grid(BLOCKS_PER_B, BN_B);
    if (ws_size >= WS_NEEDED) {
        k_reduce_solve<true><<<grid, THREADS, 0, stream>>>(r, w, J_p, J_d, lmbda, ws, out);
        k_depth2<<<grid, THREADS, 0, stream>>>((uint4*)(ws + STATE_OFF), out, out + 192);
    } else {
        k_reduce_solve<false><<<grid, THREADS, 0, stream>>>(r, w, J_p, J_d, lmbda, ws, out);
        k_depth_rc<<<grid, THREADS, 0, stream>>>(r, w, J_p, J_d, lmbda, out, out + 192);
    }
}